// Round 2
// baseline (527.465 us; speedup 1.0000x reference)
//
#include <hip/hip_runtime.h>
#include <hip/hip_bf16.h>
#include <stdint.h>

// ---------------- types & helpers ----------------
typedef __attribute__((ext_vector_type(8))) __bf16 bf16x8;
typedef __attribute__((ext_vector_type(4))) float f32x4;

#define CDIM 2048
#define DDIM 512

__device__ __forceinline__ unsigned short f2bf(float f) {
  union { float f; unsigned u; } a; a.f = f;
  unsigned r = a.u + 0x7FFFu + ((a.u >> 16) & 1u);   // RNE to bf16
  return (unsigned short)(r >> 16);
}
__device__ __forceinline__ float bf2f(unsigned short h) {
  union { unsigned u; float f; } a; a.u = ((unsigned)h) << 16;
  return a.f;
}

typedef const __attribute__((address_space(1))) void gas_void;
typedef __attribute__((address_space(3))) void las_void;
__device__ __forceinline__ void async16(const void* g, void* l) {
  // wave-uniform LDS base; HW adds lane*16 (guide §5)
  __builtin_amdgcn_global_load_lds((gas_void*)g, (las_void*)l, 16, 0, 0);
}

__device__ __forceinline__ float blockSum256(float v) {
  __shared__ float sh[4];
  #pragma unroll
  for (int o = 32; o; o >>= 1) v += __shfl_xor(v, o, 64);
  int lane = threadIdx.x & 63, w = threadIdx.x >> 6;
  __syncthreads();
  if (lane == 0) sh[w] = v;
  __syncthreads();
  return sh[0] + sh[1] + sh[2] + sh[3];
}

// Swizzled LDS fragment read: tile is [128 rows][8 chunks of 8 bf16],
// chunk stored at (cb ^ (row&7)). Matches the pre-swizzled global source.
__device__ __forceinline__ bf16x8 lds_frag(const unsigned short* base, int row, int cb) {
  return *(const bf16x8*)(base + row*64 + (((cb ^ (row & 7))) << 3));
}

// ---------------- K0: fp32 -> bf16 conversion ----------------
__global__ __launch_bounds__(256) void k_convert(const float* __restrict__ x,
    const float* __restrict__ w, uint2* __restrict__ x16, uint2* __restrict__ w16) {
  const int nx4 = 15*1024*CDIM/4;
  const int nw4 = 15*DDIM*CDIM/4;
  int stride = gridDim.x * blockDim.x;
  for (int i = blockIdx.x*blockDim.x + threadIdx.x; i < nx4; i += stride) {
    float4 v = ((const float4*)x)[i];
    x16[i] = make_uint2((unsigned)f2bf(v.x) | ((unsigned)f2bf(v.y) << 16),
                        (unsigned)f2bf(v.z) | ((unsigned)f2bf(v.w) << 16));
  }
  for (int i = blockIdx.x*blockDim.x + threadIdx.x; i < nw4; i += stride) {
    float4 v = ((const float4*)w)[i];
    w16[i] = make_uint2((unsigned)f2bf(v.x) | ((unsigned)f2bf(v.y) << 16),
                        (unsigned)f2bf(v.z) | ((unsigned)f2bf(v.w) << 16));
  }
}

// ---------------- K1: total_k = [src_k; tgt] @ W_add[ik]^T + b_add (bf16 out) ----------------
// 128x128 tile, BK=64, 4 waves (2x2), 16x16x32 bf16 MFMA, global_load_lds x16,
// T2-style XOR swizzle via pre-swizzled global source (rule 21: both sides).
__global__ __launch_bounds__(256) void k_gemm1(
    const unsigned short* __restrict__ x16,     // [15][1024][2048]
    const unsigned short* __restrict__ w16,     // [15][512][2048]
    const float* __restrict__ b_add,            // [15][512]
    const int* __restrict__ subj_p,
    unsigned short* __restrict__ t16)           // [14][2048][512]
{
  const int subj = *subj_p;
  int bid = blockIdx.x;
  int k  = bid >> 6;          // 64 tiles per k (16 m-tiles x 4 n-tiles)
  int t  = bid & 63;
  int mt = t >> 2, nt = t & 3;
  int ik = (k < subj) ? k : (k + 1);

  __shared__ unsigned short As[128*64];
  __shared__ unsigned short Bs[128*64];

  int tid = threadIdx.x;
  int lane = tid & 63;
  int w = tid >> 6;
  int wm = w >> 1, wn = w & 1;
  int rlane = lane >> 3;
  int col8  = ((lane & 7) ^ rlane) << 3;   // pre-swizzled source chunk

  const unsigned short* Bbase = w16 + (size_t)ik * DDIM * CDIM;

  f32x4 acc[4][4];
  #pragma unroll
  for (int a = 0; a < 4; a++)
    #pragma unroll
    for (int b = 0; b < 4; b++) acc[a][b] = f32x4{0.f,0.f,0.f,0.f};

  for (int ks = 0; ks < CDIM; ks += 64) {
    #pragma unroll
    for (int i = 0; i < 4; i++) {
      int c = w*4 + i;               // chunk 0..15, 8 rows each
      int r = c*8 + rlane;           // tile row 0..127
      int gr = mt*128 + r;           // global row 0..2047
      int xrow = ((gr < 1024) ? ik : subj) * 1024 + (gr & 1023);
      async16(x16 + (size_t)xrow*CDIM + ks + col8, (char*)As + c*1024);
      int gn = nt*128 + r;           // W row (output col) 0..511
      async16(Bbase + (size_t)gn*CDIM + ks + col8, (char*)Bs + c*1024);
    }
    __syncthreads();
    #pragma unroll
    for (int kk = 0; kk < 64; kk += 32) {
      bf16x8 af[4], bfr[4];
      #pragma unroll
      for (int a = 0; a < 4; a++)
        af[a] = lds_frag(As, wm*64 + a*16 + (lane & 15), (kk >> 3) + (lane >> 4));
      #pragma unroll
      for (int b = 0; b < 4; b++)
        bfr[b] = lds_frag(Bs, wn*64 + b*16 + (lane & 15), (kk >> 3) + (lane >> 4));
      #pragma unroll
      for (int a = 0; a < 4; a++)
        #pragma unroll
        for (int b = 0; b < 4; b++)
          acc[a][b] = __builtin_amdgcn_mfma_f32_16x16x32_bf16(af[a], bfr[b], acc[a][b], 0, 0, 0);
    }
    __syncthreads();
  }
  const float* bias = b_add + ik*DDIM;
  #pragma unroll
  for (int b = 0; b < 4; b++) {
    int coln = nt*128 + wn*64 + b*16 + (lane & 15);
    float bv = bias[coln];
    #pragma unroll
    for (int a = 0; a < 4; a++) {
      #pragma unroll
      for (int r = 0; r < 4; r++) {
        int rowm = mt*128 + wm*64 + a*16 + ((lane >> 4) << 2) + r;   // C layout m89/m91
        t16[((size_t)k*2048 + rowm)*DDIM + coln] = f2bf(acc[a][b][r] + bv);
      }
    }
  }
}

// ---------------- K2a: per-row sq / softmax max / inv-sumexp + fused column sums ----------------
__global__ __launch_bounds__(256) void k_rowred(const unsigned short* __restrict__ t16,
    float* __restrict__ sq, float* __restrict__ rmax, float* __restrict__ rinv,
    float* __restrict__ scol)
{
  __shared__ float cs[4][512];
  int tidx = threadIdx.x;
  int w = tidx >> 6;
  int lane = tidx & 63;
  int wid = blockIdx.x*4 + w;          // k*2048 + r ; 4 consecutive rows, same k
  int k = wid >> 11;
  uint4 v = *(const uint4*)(t16 + (size_t)wid * DDIM + lane*8);
  unsigned uu[4] = {v.x, v.y, v.z, v.w};
  float f[8];
  #pragma unroll
  for (int q = 0; q < 4; q++) {
    f[2*q]   = bf2f((unsigned short)(uu[q] & 0xffffu));
    f[2*q+1] = bf2f((unsigned short)(uu[q] >> 16));
  }
  float s2 = 0.f, mx = -3.4e38f;
  #pragma unroll
  for (int j = 0; j < 8; j++) { s2 += f[j]*f[j]; mx = fmaxf(mx, f[j]); }
  #pragma unroll
  for (int o = 32; o; o >>= 1) { s2 += __shfl_xor(s2, o, 64); mx = fmaxf(mx, __shfl_xor(mx, o, 64)); }
  float se = 0.f;
  #pragma unroll
  for (int j = 0; j < 8; j++) se += __expf(f[j] - mx);
  #pragma unroll
  for (int o = 32; o; o >>= 1) se += __shfl_xor(se, o, 64);
  if (lane == 0) { sq[wid] = s2; rmax[wid] = mx; rinv[wid] = 1.f/se; }
  // column-sum contribution (no LDS atomics: per-wave slice)
  #pragma unroll
  for (int j = 0; j < 8; j++) cs[w][lane*8 + j] = f[j];
  __syncthreads();
  atomicAdd(&scol[k*512 + tidx],       cs[0][tidx]     + cs[1][tidx]     + cs[2][tidx]     + cs[3][tidx]);
  atomicAdd(&scol[k*512 + 256 + tidx], cs[0][tidx+256] + cs[1][tidx+256] + cs[2][tidx+256] + cs[3][tidx+256]);
}

// ---------------- K2c: bandwidth -> exp2 coefficients ----------------
__global__ __launch_bounds__(256) void k_bw(const float* __restrict__ sq,
    const float* __restrict__ scol, float* __restrict__ c2)
{
  int k = blockIdx.x;
  float a = 0.f;
  for (int r = threadIdx.x; r < 2048; r += 256) a += sq[k*2048 + r];
  float b = 0.f;
  for (int d = threadIdx.x; d < 512; d += 256) { float v = scol[k*512 + d]; b += v*v; }
  float atot = blockSum256(a);
  float btot = blockSum256(b);
  if (threadIdx.x == 0) {
    // sum(d2) = 2m*sum(sq) - 2*|sum_rows|^2 ; bandwidth = sum/(m^2-m) / 2^(5//2)
    float sumd2 = 2.f*2048.f*atot - 2.f*btot;
    float bw = sumd2 / (2048.f*2048.f - 2048.f) * 0.25f;
    #pragma unroll
    for (int i = 0; i < 5; i++)
      c2[k*5 + i] = -1.4426950408889634f / (bw * (float)(1 << i));
  }
}

// ---------------- K2d: Gram + signed kernel-sum (MMD), upper-tri tiles ----------------
__global__ __launch_bounds__(256) void k_mmd(
    const unsigned short* __restrict__ t16,
    const float* __restrict__ sq,
    const float* __restrict__ c2,
    float* __restrict__ g_acc)
{
  int bid = blockIdx.x;            // k*136 + tri
  int k = bid / 136;
  int tri = bid - k*136;
  int it = 0;
  while (tri >= 16 - it) { tri -= 16 - it; it++; }
  int jt = it + tri;               // it <= jt

  const unsigned short* T = t16 + (size_t)k * 2048 * DDIM;

  __shared__ unsigned short As[128*64];
  __shared__ unsigned short Bs[128*64];
  __shared__ float sqs[256];

  int tid = threadIdx.x;
  int lane = tid & 63;
  int w = tid >> 6;
  int wm = w >> 1, wn = w & 1;
  int rlane = lane >> 3;
  int col8  = ((lane & 7) ^ rlane) << 3;   // pre-swizzled source chunk

  f32x4 acc[4][4];
  #pragma unroll
  for (int a = 0; a < 4; a++)
    #pragma unroll
    for (int b = 0; b < 4; b++) acc[a][b] = f32x4{0.f,0.f,0.f,0.f};

  for (int ks = 0; ks < DDIM; ks += 64) {
    #pragma unroll
    for (int i = 0; i < 4; i++) {
      int c = w*4 + i;
      int r = c*8 + rlane;
      async16(T + (size_t)(it*128 + r)*DDIM + ks + col8, (char*)As + c*1024);
      async16(T + (size_t)(jt*128 + r)*DDIM + ks + col8, (char*)Bs + c*1024);
    }
    __syncthreads();
    #pragma unroll
    for (int kk = 0; kk < 64; kk += 32) {
      bf16x8 af[4], bfr[4];
      #pragma unroll
      for (int a = 0; a < 4; a++)
        af[a] = lds_frag(As, wm*64 + a*16 + (lane & 15), (kk >> 3) + (lane >> 4));
      #pragma unroll
      for (int b = 0; b < 4; b++)
        bfr[b] = lds_frag(Bs, wn*64 + b*16 + (lane & 15), (kk >> 3) + (lane >> 4));
      #pragma unroll
      for (int a = 0; a < 4; a++)
        #pragma unroll
        for (int b = 0; b < 4; b++)
          acc[a][b] = __builtin_amdgcn_mfma_f32_16x16x32_bf16(af[a], bfr[b], acc[a][b], 0, 0, 0);
    }
    __syncthreads();
  }
  if (tid < 128) sqs[tid] = sq[k*2048 + it*128 + tid];
  else           sqs[tid] = sq[k*2048 + jt*128 + (tid - 128)];
  __syncthreads();

  float c0 = c2[k*5], c1 = c2[k*5+1], cA = c2[k*5+2], c3 = c2[k*5+3], c4 = c2[k*5+4];
  float part = 0.f;
  #pragma unroll
  for (int a = 0; a < 4; a++) {
    #pragma unroll
    for (int b = 0; b < 4; b++) {
      int rj = wn*64 + b*16 + (lane & 15);
      float sj = sqs[128 + rj];
      #pragma unroll
      for (int r = 0; r < 4; r++) {
        int ri = wm*64 + a*16 + ((lane >> 4) << 2) + r;
        float d2 = sqs[ri] + sj - 2.f*acc[a][b][r];
        part += exp2f(c0*d2) + exp2f(c1*d2) + exp2f(cA*d2) + exp2f(c3*d2) + exp2f(c4*d2);
      }
    }
  }
  float tot = blockSum256(part);
  if (tid == 0) {
    float sgn = ((it < 8) == (jt < 8)) ? 1.f : -1.f;   // XX/YY: + ; XY/YX: -
    float wgt = (it == jt) ? 1.f : 2.f;                 // symmetry
    atomicAdd(&g_acc[k], sgn * wgt * tot);
  }
}

// ---------------- K3: heads = disc + logits(+cls KL, +pred accum) fused ----------------
// blocks [0,2048)           : disc pairwise |P_i - P_j|
// blocks [2048, 2048+7168)  : per-row logits -> KL (src) / prob accum (tgt)
__global__ __launch_bounds__(256) void k_heads(const unsigned short* __restrict__ t16,
    const float* __restrict__ rmax, const float* __restrict__ rinv,
    const float* __restrict__ W_cls, const float* __restrict__ b_cls,
    const float* __restrict__ y, const int* __restrict__ subj_p,
    float* __restrict__ g_acc, float* __restrict__ pacc)
{
  if (blockIdx.x < 2048) {
    int b = blockIdx.x;              // 1024 rows x 2 half-rows
    int row = b >> 1;                // source rows only
    int d = ((b & 1) << 8) + threadIdx.x;
    float p[14];
    #pragma unroll
    for (int k = 0; k < 14; k++) {
      float tv = bf2f(t16[((size_t)(k*2048 + row))*DDIM + d]);
      p[k] = __expf(tv - rmax[k*2048 + row]) * rinv[k*2048 + row];
    }
    float s = 0.f;
    #pragma unroll
    for (int i2 = 0; i2 < 14; i2++)
      #pragma unroll
      for (int j2 = i2+1; j2 < 14; j2++)
        s += fabsf(p[i2] - p[j2]);
    float tot = blockSum256(s);
    if (threadIdx.x == 0) atomicAdd(&g_acc[14 + (b & 7)], tot);
  } else {
    __shared__ float shk[4];
    int bid = blockIdx.x - 2048;
    int w = threadIdx.x >> 6;
    int lane = threadIdx.x & 63;
    int wid = bid*4 + w;             // k*2048 + r (4 rows, same k, same half)
    int k = wid >> 11, r = wid & 2047;
    uint4 v = *(const uint4*)(t16 + (size_t)wid * DDIM + lane*8);
    unsigned uu[4] = {v.x, v.y, v.z, v.w};
    float f[8];
    #pragma unroll
    for (int q = 0; q < 4; q++) {
      f[2*q]   = fmaxf(bf2f((unsigned short)(uu[q] & 0xffffu)), 0.f);
      f[2*q+1] = fmaxf(bf2f((unsigned short)(uu[q] >> 16)), 0.f);
    }
    const float* Wc = W_cls + k*3*DDIM;
    int d0 = lane*8;
    float l0 = 0.f, l1 = 0.f, l2 = 0.f;
    #pragma unroll
    for (int j = 0; j < 8; j++) {
      l0 += f[j]*Wc[d0+j];
      l1 += f[j]*Wc[DDIM + d0+j];
      l2 += f[j]*Wc[2*DDIM + d0+j];
    }
    #pragma unroll
    for (int o = 32; o; o >>= 1) {
      l0 += __shfl_xor(l0, o, 64); l1 += __shfl_xor(l1, o, 64); l2 += __shfl_xor(l2, o, 64);
    }
    if (r < 1024) {                  // src rows -> cls KL
      float kl = 0.f;
      if (lane == 0) {
        l0 += b_cls[k*3+0]; l1 += b_cls[k*3+1]; l2 += b_cls[k*3+2];
        float mx = fmaxf(l0, fmaxf(l1, l2));
        float lse = mx + __logf(__expf(l0-mx) + __expf(l1-mx) + __expf(l2-mx));
        int subj = *subj_p;
        int ik = (k < subj) ? k : k+1;
        const float* yr = y + ((size_t)(ik*1024 + r))*3;
        float tl = (yr[0] > 0.5f) ? l0 : ((yr[1] > 0.5f) ? l1 : l2);
        kl = lse - tl;
        shk[w] = kl;
      }
      __syncthreads();
      if (threadIdx.x == 0)
        atomicAdd(&g_acc[22 + k], shk[0] + shk[1] + shk[2] + shk[3]);
    } else {                         // tgt rows -> pred prob accumulation
      if (lane == 0) {
        l0 += b_cls[k*3+0]; l1 += b_cls[k*3+1]; l2 += b_cls[k*3+2];
        float mx = fmaxf(l0, fmaxf(l1, l2));
        float e0 = __expf(l0-mx), e1 = __expf(l1-mx), e2 = __expf(l2-mx);
        float inv = 1.f/(e0+e1+e2);
        int j = r - 1024;
        atomicAdd(&pacc[j*3 + 0], e0*inv);
        atomicAdd(&pacc[j*3 + 1], e1*inv);
        atomicAdd(&pacc[j*3 + 2], e2*inv);
      }
    }
  }
}

// ---------------- K6: pred (argmax of summed softmax over k) ----------------
__global__ __launch_bounds__(256) void k_pred(const float* __restrict__ pacc,
    const float* __restrict__ y, const int* __restrict__ subj_p, float* __restrict__ g_acc)
{
  int j = blockIdx.x*256 + threadIdx.x;   // 0..1023
  int subj = *subj_p;
  float p0 = pacc[j*3+0], p1 = pacc[j*3+1], p2 = pacc[j*3+2];
  int pa = 0; float pm = p0;
  if (p1 > pm) { pa = 1; pm = p1; }
  if (p2 > pm) { pa = 2; }
  const float* yt = y + ((size_t)(subj*1024 + j))*3;
  int ya = 0; float ym = yt[0];
  if (yt[1] > ym) { ya = 1; ym = yt[1]; }
  if (yt[2] > ym) { ya = 2; }
  float tot = blockSum256((pa == ya) ? 1.f : 0.f);
  if (threadIdx.x == 0) atomicAdd(&g_acc[36], tot);
}

// ---------------- K7: finalize ----------------
__global__ void k_fin(const float* __restrict__ g_acc, float* __restrict__ out)
{
  if (threadIdx.x == 0 && blockIdx.x == 0) {
    float s = 0.f;
    for (int k = 0; k < 14; k++) s += g_acc[k];
    float disc = 0.f;
    for (int i = 14; i < 22; i++) disc += g_acc[i];
    float cls = 0.f;
    for (int i = 22; i < 36; i++) cls += g_acc[i];
    out[0] = 0.1f * s / (14.f * 1024.f * 1024.f);
    out[1] = 0.4f * disc * (2.f / (14.f*13.f)) / (1024.f*512.f);
    out[2] = cls / (14.f*1024.f);
    out[3] = g_acc[36];
    out[4] = 1024.f;
  }
}

// ---------------- launch ----------------
extern "C" void kernel_launch(void* const* d_in, const int* in_sizes, int n_in,
                              void* d_out, int out_size, void* d_ws, size_t ws_size,
                              hipStream_t stream)
{
  (void)in_sizes; (void)n_in; (void)out_size; (void)ws_size;
  const float* x     = (const float*)d_in[0];
  const float* y     = (const float*)d_in[1];
  const float* W_add = (const float*)d_in[3];
  const float* b_add = (const float*)d_in[4];
  const float* W_cls = (const float*)d_in[5];
  const float* b_cls = (const float*)d_in[6];
  const int*   subj  = (const int*)d_in[7];

  char* ws = (char*)d_ws;
  size_t o = 0;
  auto take = [&](size_t b) { char* p = ws + o; o += (b + 255) & ~(size_t)255; return p; };
  unsigned short* X16 = (unsigned short*)take((size_t)15*1024*2048*2);   // 63 MB
  unsigned short* W16 = (unsigned short*)take((size_t)15*512*2048*2);    // 31.5 MB
  unsigned short* T16 = (unsigned short*)take((size_t)14*2048*512*2);    // 29.4 MB
  float* SQ   = (float*)take((size_t)14*2048*4);
  float* RMAX = (float*)take((size_t)14*2048*4);
  float* RINV = (float*)take((size_t)14*2048*4);
  float* C2   = (float*)take(512);
  // zero-init region (single memset): SCOL | PACC | ACC
  float* SCOL = (float*)take((size_t)14*512*4);     // 28672 B
  float* PACC = (float*)take((size_t)1024*3*4);     // 12288 B
  float* ACC  = (float*)take(256);                  // [0..13] mmd, [14..21] disc, [22..35] cls, [36] pred

  hipMemsetAsync(SCOL, 0, 14*512*4 + 1024*3*4 + 256, stream);

  k_convert<<<2048, 256, 0, stream>>>(x, W_add, (uint2*)X16, (uint2*)W16);
  k_gemm1 <<<14*64, 256, 0, stream>>>(X16, W16, b_add, subj, T16);
  k_rowred<<<14*2048/4, 256, 0, stream>>>(T16, SQ, RMAX, RINV, SCOL);
  k_bw    <<<14, 256, 0, stream>>>(SQ, SCOL, C2);
  k_mmd   <<<14*136, 256, 0, stream>>>(T16, SQ, C2, ACC);
  k_heads <<<2048 + 14*2048/4, 256, 0, stream>>>(T16, RMAX, RINV, W_cls, b_cls, y, subj, ACC, PACC);
  k_pred  <<<4, 256, 0, stream>>>(PACC, y, subj, ACC);
  k_fin   <<<1, 64, 0, stream>>>(ACC, (float*)d_out);
}

// Round 3
// 502.011 us; speedup vs baseline: 1.0507x; 1.0507x over previous
//
#include <hip/hip_runtime.h>
#include <hip/hip_bf16.h>
#include <stdint.h>

// ---------------- types & helpers ----------------
typedef __attribute__((ext_vector_type(8))) __bf16 bf16x8;
typedef __attribute__((ext_vector_type(4))) float f32x4;

#define CDIM 2048
#define DDIM 512

__device__ __forceinline__ unsigned short f2bf(float f) {
  union { float f; unsigned u; } a; a.f = f;
  unsigned r = a.u + 0x7FFFu + ((a.u >> 16) & 1u);   // RNE to bf16
  return (unsigned short)(r >> 16);
}
__device__ __forceinline__ float bf2f(unsigned short h) {
  union { unsigned u; float f; } a; a.u = ((unsigned)h) << 16;
  return a.f;
}

typedef const __attribute__((address_space(1))) void gas_void;
typedef __attribute__((address_space(3))) void las_void;
__device__ __forceinline__ void async16(const void* g, void* l) {
  // wave-uniform LDS base; HW adds lane*16 (guide §5)
  __builtin_amdgcn_global_load_lds((gas_void*)g, (las_void*)l, 16, 0, 0);
}

#define VMW(n) asm volatile("s_waitcnt vmcnt(" #n ")" ::: "memory")
#define SBAR() __builtin_amdgcn_s_barrier()
#define SFENCE() __builtin_amdgcn_sched_barrier(0)

__device__ __forceinline__ float blockSum256(float v) {
  __shared__ float sh[4];
  #pragma unroll
  for (int o = 32; o; o >>= 1) v += __shfl_xor(v, o, 64);
  int lane = threadIdx.x & 63, w = threadIdx.x >> 6;
  __syncthreads();
  if (lane == 0) sh[w] = v;
  __syncthreads();
  return sh[0] + sh[1] + sh[2] + sh[3];
}

// Swizzled LDS fragment read: tile rows of 64 bf16 (8 chunks of 16B),
// chunk stored at (cb ^ (row&7)). Matches the pre-swizzled global source.
__device__ __forceinline__ bf16x8 lds_frag(const unsigned short* base, int row, int cb) {
  return *(const bf16x8*)(base + row*64 + (((cb ^ (row & 7))) << 3));
}

// ---------------- K0: fp32 -> bf16 conversion ----------------
__global__ __launch_bounds__(256) void k_convert(const float* __restrict__ x,
    const float* __restrict__ w, uint2* __restrict__ x16, uint2* __restrict__ w16) {
  const int nx4 = 15*1024*CDIM/4;
  const int nw4 = 15*DDIM*CDIM/4;
  int stride = gridDim.x * blockDim.x;
  for (int i = blockIdx.x*blockDim.x + threadIdx.x; i < nx4; i += stride) {
    float4 v = ((const float4*)x)[i];
    x16[i] = make_uint2((unsigned)f2bf(v.x) | ((unsigned)f2bf(v.y) << 16),
                        (unsigned)f2bf(v.z) | ((unsigned)f2bf(v.w) << 16));
  }
  for (int i = blockIdx.x*blockDim.x + threadIdx.x; i < nw4; i += stride) {
    float4 v = ((const float4*)w)[i];
    w16[i] = make_uint2((unsigned)f2bf(v.x) | ((unsigned)f2bf(v.y) << 16),
                        (unsigned)f2bf(v.z) | ((unsigned)f2bf(v.w) << 16));
  }
}

// ---------------- K1: total_k = [src_k; tgt] @ W_add[ik]^T + b_add (bf16 out) ----------------
// Depth-2 pipeline: BM=128 BN=256 BK=64, 8 waves (2Mx4N), 3 LDS buffers (144KB),
// counted vmcnt(6) (T4), raw s_barrier, swizzled staging (T2), setprio (T5).
__global__ __launch_bounds__(512, 2) void k_gemm1(
    const unsigned short* __restrict__ x16,     // [15][1024][2048]
    const unsigned short* __restrict__ w16,     // [15][512][2048]
    const float* __restrict__ b_add,            // [15][512]
    const int* __restrict__ subj_p,
    unsigned short* __restrict__ t16)           // [14][2048][512]
{
  const int subj = *subj_p;
  int bid = blockIdx.x;
  int k  = bid >> 5;          // 32 tiles per k (16 m-tiles x 2 n-tiles)
  int t  = bid & 31;
  int mt = t >> 1, nt = t & 1;
  int ik = (k < subj) ? k : (k + 1);

  __shared__ unsigned short lds[3*384*64];   // buf: A[128][64] @0, B[256][64] @8192

  int tid = threadIdx.x;
  int lane = tid & 63;
  int w = tid >> 6;           // 0..7
  int wm = w >> 2, wn = w & 3;
  int rr = lane >> 3;
  int cc8 = ((lane & 7) ^ rr) << 3;   // pre-swizzled source chunk (r0 is 8-aligned)

  const unsigned short* Bb = w16 + (size_t)ik * DDIM * CDIM;

  f32x4 acc[4][4];
  #pragma unroll
  for (int a = 0; a < 4; a++)
    #pragma unroll
    for (int b = 0; b < 4; b++) acc[a][b] = f32x4{0.f,0.f,0.f,0.f};

  auto stage = [&](int tt, int bufi) {
    unsigned short* buf = lds + bufi*(384*64);
    int ks = tt*64;
    #pragma unroll
    for (int i = 0; i < 2; i++) {           // A: 16 pieces, 2 per wave
      int r0 = (w*2 + i)*8;
      int gr = mt*128 + r0 + rr;
      int xrow = ((gr < 1024) ? ik : subj)*1024 + (gr & 1023);
      async16(x16 + (size_t)xrow*CDIM + ks + cc8, buf + r0*64);
    }
    #pragma unroll
    for (int i = 0; i < 4; i++) {           // B: 32 pieces, 4 per wave
      int r0 = (w*4 + i)*8;
      int gn = nt*256 + r0 + rr;
      async16(Bb + (size_t)gn*CDIM + ks + cc8, buf + 8192 + r0*64);
    }
  };

  auto compute = [&](int bufi) {
    const unsigned short* A = lds + bufi*(384*64);
    const unsigned short* B = A + 8192;
    bf16x8 af[4][2], bfr[4][2];
    #pragma unroll
    for (int a = 0; a < 4; a++)
      #pragma unroll
      for (int ksl = 0; ksl < 2; ksl++)
        af[a][ksl] = lds_frag(A, wm*64 + a*16 + (lane & 15), ksl*4 + (lane >> 4));
    #pragma unroll
    for (int bb = 0; bb < 4; bb++)
      #pragma unroll
      for (int ksl = 0; ksl < 2; ksl++)
        bfr[bb][ksl] = lds_frag(B, wn*64 + bb*16 + (lane & 15), ksl*4 + (lane >> 4));
    __builtin_amdgcn_s_setprio(1);
    #pragma unroll
    for (int a = 0; a < 4; a++)
      #pragma unroll
      for (int bb = 0; bb < 4; bb++) {
        acc[a][bb] = __builtin_amdgcn_mfma_f32_16x16x32_bf16(af[a][0], bfr[bb][0], acc[a][bb], 0, 0, 0);
        acc[a][bb] = __builtin_amdgcn_mfma_f32_16x16x32_bf16(af[a][1], bfr[bb][1], acc[a][bb], 0, 0, 0);
      }
    __builtin_amdgcn_s_setprio(0);
  };

  stage(0, 0);
  stage(1, 1);
  VMW(6); SBAR(); SFENCE();                 // tile0 staged (12 out -> wait oldest 6)

  int cur = 0;
  for (int tt = 0; tt < 30; ++tt) {
    int nb = cur + 2; if (nb >= 3) nb -= 3;
    stage(tt + 2, nb);                      // prefetch depth 2
    compute(cur);
    VMW(6); SBAR(); SFENCE();               // tile tt+1 staged; never drain to 0
    cur = (cur == 2) ? 0 : cur + 1;
  }
  compute(cur);                             // tile 30
  VMW(0); SBAR(); SFENCE();                 // tail: tile 31 fully staged
  cur = (cur == 2) ? 0 : cur + 1;
  compute(cur);                             // tile 31

  const float* bias = b_add + ik*DDIM;
  #pragma unroll
  for (int bb = 0; bb < 4; bb++) {
    int coln = nt*256 + wn*64 + bb*16 + (lane & 15);
    float bv = bias[coln];
    #pragma unroll
    for (int a = 0; a < 4; a++) {
      #pragma unroll
      for (int r = 0; r < 4; r++) {
        int rowm = mt*128 + wm*64 + a*16 + ((lane >> 4) << 2) + r;   // C layout m89/m91
        t16[((size_t)k*2048 + rowm)*DDIM + coln] = f2bf(acc[a][bb][r] + bv);
      }
    }
  }
}

// ---------------- K2a: per-row sq / softmax max / inv-sumexp ----------------
__global__ __launch_bounds__(256) void k_rowred(const unsigned short* __restrict__ t16,
    float* __restrict__ sq, float* __restrict__ rmax, float* __restrict__ rinv)
{
  int wid = blockIdx.x*4 + (threadIdx.x >> 6);   // 0..28671 = k*2048 + r
  int lane = threadIdx.x & 63;
  uint4 v = *(const uint4*)(t16 + (size_t)wid * DDIM + lane*8);
  unsigned uu[4] = {v.x, v.y, v.z, v.w};
  float f[8];
  #pragma unroll
  for (int q = 0; q < 4; q++) {
    f[2*q]   = bf2f((unsigned short)(uu[q] & 0xffffu));
    f[2*q+1] = bf2f((unsigned short)(uu[q] >> 16));
  }
  float s2 = 0.f, mx = -3.4e38f;
  #pragma unroll
  for (int j = 0; j < 8; j++) { s2 += f[j]*f[j]; mx = fmaxf(mx, f[j]); }
  #pragma unroll
  for (int o = 32; o; o >>= 1) { s2 += __shfl_xor(s2, o, 64); mx = fmaxf(mx, __shfl_xor(mx, o, 64)); }
  float se = 0.f;
  #pragma unroll
  for (int j = 0; j < 8; j++) se += __expf(f[j] - mx);
  #pragma unroll
  for (int o = 32; o; o >>= 1) se += __shfl_xor(se, o, 64);
  if (lane == 0) { sq[wid] = s2; rmax[wid] = mx; rinv[wid] = 1.f/se; }
}

// ---------------- K2b: column sums (for analytic sum(d2)) ----------------
__global__ __launch_bounds__(256) void k_colsum(const unsigned short* __restrict__ t16,
    float* __restrict__ scol)
{
  int b = blockIdx.x;              // 14*16
  int k = b >> 4, sub = b & 15;
  int d = ((sub & 1) << 8) + threadIdx.x;
  int r0 = (sub >> 1) << 8;
  const unsigned short* base = t16 + (size_t)k*2048*DDIM;
  float s = 0.f;
  for (int r = r0; r < r0 + 256; r++) s += bf2f(base[(size_t)r*DDIM + d]);
  atomicAdd(&scol[k*DDIM + d], s);
}

// ---------------- K2c: bandwidth -> exp2 coefficients ----------------
__global__ __launch_bounds__(256) void k_bw(const float* __restrict__ sq,
    const float* __restrict__ scol, float* __restrict__ c2)
{
  int k = blockIdx.x;
  float a = 0.f;
  for (int r = threadIdx.x; r < 2048; r += 256) a += sq[k*2048 + r];
  float b = 0.f;
  for (int d = threadIdx.x; d < 512; d += 256) { float v = scol[k*512 + d]; b += v*v; }
  float atot = blockSum256(a);
  float btot = blockSum256(b);
  if (threadIdx.x == 0) {
    // sum(d2) = 2m*sum(sq) - 2*|sum_rows|^2 ; bandwidth = sum/(m^2-m) / 2^(5//2)
    float sumd2 = 2.f*2048.f*atot - 2.f*btot;
    float bw = sumd2 / (2048.f*2048.f - 2048.f) * 0.25f;
    #pragma unroll
    for (int i = 0; i < 5; i++)
      c2[k*5 + i] = -1.4426950408889634f / (bw * (float)(1 << i));
  }
}

// ---------------- K2d: Gram + signed kernel-sum (MMD), upper-tri tiles ----------------
// Same depth-2 counted-vmcnt skeleton: 128x128 tile, 4 waves, 3 bufs (96KB), NT=8.
__global__ __launch_bounds__(256, 1) void k_mmd(
    const unsigned short* __restrict__ t16,
    const float* __restrict__ sq,
    const float* __restrict__ c2,
    float* __restrict__ g_acc)
{
  int bid = blockIdx.x;            // k*136 + tri
  int k = bid / 136;
  int tri = bid - k*136;
  int it = 0;
  while (tri >= 16 - it) { tri -= 16 - it; it++; }
  int jt = it + tri;               // it <= jt

  const unsigned short* T = t16 + (size_t)k * 2048 * DDIM;

  __shared__ unsigned short lds[3*256*64];  // buf: A[128][64] @0, B[128][64] @8192
  __shared__ float sqs[256];

  int tid = threadIdx.x;
  int lane = tid & 63;
  int w = tid >> 6;                // 0..3
  int wm = w >> 1, wn = w & 1;
  int rr = lane >> 3;
  int cc8 = ((lane & 7) ^ rr) << 3;

  f32x4 acc[4][4];
  #pragma unroll
  for (int a = 0; a < 4; a++)
    #pragma unroll
    for (int b = 0; b < 4; b++) acc[a][b] = f32x4{0.f,0.f,0.f,0.f};

  auto stage = [&](int tt, int bufi) {
    unsigned short* buf = lds + bufi*(256*64);
    int ks = tt*64;
    #pragma unroll
    for (int i = 0; i < 4; i++) {           // A: 16 pieces, 4 per wave
      int r0 = (w*4 + i)*8;
      async16(T + (size_t)(it*128 + r0 + rr)*DDIM + ks + cc8, buf + r0*64);
    }
    #pragma unroll
    for (int i = 0; i < 4; i++) {           // B: 16 pieces, 4 per wave
      int r0 = (w*4 + i)*8;
      async16(T + (size_t)(jt*128 + r0 + rr)*DDIM + ks + cc8, buf + 8192 + r0*64);
    }
  };

  auto compute = [&](int bufi) {
    const unsigned short* A = lds + bufi*(256*64);
    const unsigned short* B = A + 8192;
    bf16x8 af[4][2], bfr[4][2];
    #pragma unroll
    for (int a = 0; a < 4; a++)
      #pragma unroll
      for (int ksl = 0; ksl < 2; ksl++)
        af[a][ksl] = lds_frag(A, wm*64 + a*16 + (lane & 15), ksl*4 + (lane >> 4));
    #pragma unroll
    for (int bb = 0; bb < 4; bb++)
      #pragma unroll
      for (int ksl = 0; ksl < 2; ksl++)
        bfr[bb][ksl] = lds_frag(B, wn*64 + bb*16 + (lane & 15), ksl*4 + (lane >> 4));
    __builtin_amdgcn_s_setprio(1);
    #pragma unroll
    for (int a = 0; a < 4; a++)
      #pragma unroll
      for (int bb = 0; bb < 4; bb++) {
        acc[a][bb] = __builtin_amdgcn_mfma_f32_16x16x32_bf16(af[a][0], bfr[bb][0], acc[a][bb], 0, 0, 0);
        acc[a][bb] = __builtin_amdgcn_mfma_f32_16x16x32_bf16(af[a][1], bfr[bb][1], acc[a][bb], 0, 0, 0);
      }
    __builtin_amdgcn_s_setprio(0);
  };

  stage(0, 0);
  stage(1, 1);
  VMW(8); SBAR(); SFENCE();

  int cur = 0;
  for (int tt = 0; tt < 6; ++tt) {
    int nb = cur + 2; if (nb >= 3) nb -= 3;
    stage(tt + 2, nb);
    compute(cur);
    VMW(8); SBAR(); SFENCE();
    cur = (cur == 2) ? 0 : cur + 1;
  }
  compute(cur);                             // tile 6
  VMW(0); SBAR(); SFENCE();
  cur = (cur == 2) ? 0 : cur + 1;
  compute(cur);                             // tile 7

  if (tid < 128) sqs[tid] = sq[k*2048 + it*128 + tid];
  else           sqs[tid] = sq[k*2048 + jt*128 + (tid - 128)];
  __syncthreads();

  float c0 = c2[k*5], c1 = c2[k*5+1], cA = c2[k*5+2], c3 = c2[k*5+3], c4 = c2[k*5+4];
  float part = 0.f;
  #pragma unroll
  for (int a = 0; a < 4; a++) {
    #pragma unroll
    for (int bb = 0; bb < 4; bb++) {
      int rj = wn*64 + bb*16 + (lane & 15);
      float sj = sqs[128 + rj];
      #pragma unroll
      for (int r = 0; r < 4; r++) {
        int ri = wm*64 + a*16 + ((lane >> 4) << 2) + r;
        float d2 = sqs[ri] + sj - 2.f*acc[a][bb][r];
        part += exp2f(c0*d2) + exp2f(c1*d2) + exp2f(cA*d2) + exp2f(c3*d2) + exp2f(c4*d2);
      }
    }
  }
  float tot = blockSum256(part);
  if (tid == 0) {
    float sgn = ((it < 8) == (jt < 8)) ? 1.f : -1.f;   // XX/YY: + ; XY/YX: -
    float wgt = (it == jt) ? 1.f : 2.f;                 // symmetry
    atomicAdd(&g_acc[k], sgn * wgt * tot);
  }
}

// ---------------- K3: heads = disc + logits(+cls KL, +pred accum) fused ----------------
__global__ __launch_bounds__(256) void k_heads(const unsigned short* __restrict__ t16,
    const float* __restrict__ rmax, const float* __restrict__ rinv,
    const float* __restrict__ W_cls, const float* __restrict__ b_cls,
    const float* __restrict__ y, const int* __restrict__ subj_p,
    float* __restrict__ g_acc, float* __restrict__ pacc)
{
  if (blockIdx.x < 2048) {
    int b = blockIdx.x;              // 1024 rows x 2 half-rows
    int row = b >> 1;                // source rows only
    int d = ((b & 1) << 8) + threadIdx.x;
    float p[14];
    #pragma unroll
    for (int k = 0; k < 14; k++) {
      float tv = bf2f(t16[((size_t)(k*2048 + row))*DDIM + d]);
      p[k] = __expf(tv - rmax[k*2048 + row]) * rinv[k*2048 + row];
    }
    float s = 0.f;
    #pragma unroll
    for (int i2 = 0; i2 < 14; i2++)
      #pragma unroll
      for (int j2 = i2+1; j2 < 14; j2++)
        s += fabsf(p[i2] - p[j2]);
    float tot = blockSum256(s);
    if (threadIdx.x == 0) atomicAdd(&g_acc[14 + (b & 7)], tot);
  } else {
    __shared__ float shk[4];
    int bid = blockIdx.x - 2048;
    int w = threadIdx.x >> 6;
    int lane = threadIdx.x & 63;
    int wid = bid*4 + w;             // k*2048 + r (4 rows, same k, same half)
    int k = wid >> 11, r = wid & 2047;
    uint4 v = *(const uint4*)(t16 + (size_t)wid * DDIM + lane*8);
    unsigned uu[4] = {v.x, v.y, v.z, v.w};
    float f[8];
    #pragma unroll
    for (int q = 0; q < 4; q++) {
      f[2*q]   = fmaxf(bf2f((unsigned short)(uu[q] & 0xffffu)), 0.f);
      f[2*q+1] = fmaxf(bf2f((unsigned short)(uu[q] >> 16)), 0.f);
    }
    const float* Wc = W_cls + k*3*DDIM;
    int d0 = lane*8;
    float l0 = 0.f, l1 = 0.f, l2 = 0.f;
    #pragma unroll
    for (int j = 0; j < 8; j++) {
      l0 += f[j]*Wc[d0+j];
      l1 += f[j]*Wc[DDIM + d0+j];
      l2 += f[j]*Wc[2*DDIM + d0+j];
    }
    #pragma unroll
    for (int o = 32; o; o >>= 1) {
      l0 += __shfl_xor(l0, o, 64); l1 += __shfl_xor(l1, o, 64); l2 += __shfl_xor(l2, o, 64);
    }
    if (r < 1024) {                  // src rows -> cls KL
      if (lane == 0) {
        l0 += b_cls[k*3+0]; l1 += b_cls[k*3+1]; l2 += b_cls[k*3+2];
        float mx = fmaxf(l0, fmaxf(l1, l2));
        float lse = mx + __logf(__expf(l0-mx) + __expf(l1-mx) + __expf(l2-mx));
        int subj = *subj_p;
        int ik = (k < subj) ? k : k+1;
        const float* yr = y + ((size_t)(ik*1024 + r))*3;
        float tl = (yr[0] > 0.5f) ? l0 : ((yr[1] > 0.5f) ? l1 : l2);
        shk[w] = lse - tl;
      }
      __syncthreads();
      if (threadIdx.x == 0)
        atomicAdd(&g_acc[22 + k], shk[0] + shk[1] + shk[2] + shk[3]);
    } else {                         // tgt rows -> pred prob accumulation
      if (lane == 0) {
        l0 += b_cls[k*3+0]; l1 += b_cls[k*3+1]; l2 += b_cls[k*3+2];
        float mx = fmaxf(l0, fmaxf(l1, l2));
        float e0 = __expf(l0-mx), e1 = __expf(l1-mx), e2 = __expf(l2-mx);
        float inv = 1.f/(e0+e1+e2);
        int j = r - 1024;
        atomicAdd(&pacc[j*3 + 0], e0*inv);
        atomicAdd(&pacc[j*3 + 1], e1*inv);
        atomicAdd(&pacc[j*3 + 2], e2*inv);
      }
    }
  }
}

// ---------------- K6: pred (argmax of summed softmax over k) ----------------
__global__ __launch_bounds__(256) void k_pred(const float* __restrict__ pacc,
    const float* __restrict__ y, const int* __restrict__ subj_p, float* __restrict__ g_acc)
{
  int j = blockIdx.x*256 + threadIdx.x;   // 0..1023
  int subj = *subj_p;
  float p0 = pacc[j*3+0], p1 = pacc[j*3+1], p2 = pacc[j*3+2];
  int pa = 0; float pm = p0;
  if (p1 > pm) { pa = 1; pm = p1; }
  if (p2 > pm) { pa = 2; }
  const float* yt = y + ((size_t)(subj*1024 + j))*3;
  int ya = 0; float ym = yt[0];
  if (yt[1] > ym) { ya = 1; ym = yt[1]; }
  if (yt[2] > ym) { ya = 2; }
  float tot = blockSum256((pa == ya) ? 1.f : 0.f);
  if (threadIdx.x == 0) atomicAdd(&g_acc[36], tot);
}

// ---------------- K7: finalize ----------------
__global__ void k_fin(const float* __restrict__ g_acc, float* __restrict__ out)
{
  if (threadIdx.x == 0 && blockIdx.x == 0) {
    float s = 0.f;
    for (int k = 0; k < 14; k++) s += g_acc[k];
    float disc = 0.f;
    for (int i = 14; i < 22; i++) disc += g_acc[i];
    float cls = 0.f;
    for (int i = 22; i < 36; i++) cls += g_acc[i];
    out[0] = 0.1f * s / (14.f * 1024.f * 1024.f);
    out[1] = 0.4f * disc * (2.f / (14.f*13.f)) / (1024.f*512.f);
    out[2] = cls / (14.f*1024.f);
    out[3] = g_acc[36];
    out[4] = 1024.f;
  }
}

// ---------------- launch ----------------
extern "C" void kernel_launch(void* const* d_in, const int* in_sizes, int n_in,
                              void* d_out, int out_size, void* d_ws, size_t ws_size,
                              hipStream_t stream)
{
  (void)in_sizes; (void)n_in; (void)out_size; (void)ws_size;
  const float* x     = (const float*)d_in[0];
  const float* y     = (const float*)d_in[1];
  const float* W_add = (const float*)d_in[3];
  const float* b_add = (const float*)d_in[4];
  const float* W_cls = (const float*)d_in[5];
  const float* b_cls = (const float*)d_in[6];
  const int*   subj  = (const int*)d_in[7];

  char* ws = (char*)d_ws;
  size_t o = 0;
  auto take = [&](size_t b) { char* p = ws + o; o += (b + 255) & ~(size_t)255; return p; };
  unsigned short* X16 = (unsigned short*)take((size_t)15*1024*2048*2);   // 63 MB
  unsigned short* W16 = (unsigned short*)take((size_t)15*512*2048*2);    // 31.5 MB
  unsigned short* T16 = (unsigned short*)take((size_t)14*2048*512*2);    // 29.4 MB
  float* SQ   = (float*)take((size_t)14*2048*4);
  float* RMAX = (float*)take((size_t)14*2048*4);
  float* RINV = (float*)take((size_t)14*2048*4);
  float* C2   = (float*)take(512);
  // zero-init region (single memset): SCOL | PACC | ACC
  float* SCOL = (float*)take((size_t)14*512*4);     // 28672 B
  float* PACC = (float*)take((size_t)1024*3*4);     // 12288 B
  float* ACC  = (float*)take(256);                  // [0..13] mmd, [14..21] disc, [22..35] cls, [36] pred

  hipMemsetAsync(SCOL, 0, 14*512*4 + 1024*3*4 + 256, stream);

  k_convert<<<2048, 256, 0, stream>>>(x, W_add, (uint2*)X16, (uint2*)W16);
  k_gemm1 <<<14*32, 512, 0, stream>>>(X16, W16, b_add, subj, T16);
  k_rowred<<<14*2048/4, 256, 0, stream>>>(T16, SQ, RMAX, RINV);
  k_colsum<<<14*16, 256, 0, stream>>>(T16, SCOL);
  k_bw    <<<14, 256, 0, stream>>>(SQ, SCOL, C2);
  k_mmd   <<<14*136, 256, 0, stream>>>(T16, SQ, C2, ACC);
  k_heads <<<2048 + 14*2048/4, 256, 0, stream>>>(T16, RMAX, RINV, W_cls, b_cls, y, subj, ACC, PACC);
  k_pred  <<<4, 256, 0, stream>>>(PACC, y, subj, ACC);
  k_fin   <<<1, 64, 0, stream>>>(ACC, (float*)d_out);
}

// Round 6
// 451.866 us; speedup vs baseline: 1.1673x; 1.1110x over previous
//
#include <hip/hip_runtime.h>
#include <hip/hip_bf16.h>
#include <stdint.h>

// ---------------- types & helpers ----------------
typedef __attribute__((ext_vector_type(8))) __bf16 bf16x8;
typedef __attribute__((ext_vector_type(4))) float f32x4;

#define CDIM 2048
#define DDIM 512

__device__ __forceinline__ unsigned short f2bf(float f) {
  union { float f; unsigned u; } a; a.f = f;
  unsigned r = a.u + 0x7FFFu + ((a.u >> 16) & 1u);   // RNE to bf16
  return (unsigned short)(r >> 16);
}
__device__ __forceinline__ float bf2f(unsigned short h) {
  union { unsigned u; float f; } a; a.u = ((unsigned)h) << 16;
  return a.f;
}

typedef const __attribute__((address_space(1))) void gas_void;
typedef __attribute__((address_space(3))) void las_void;
__device__ __forceinline__ void async16(const void* g, void* l) {
  // wave-uniform LDS base; HW adds lane*16 (guide §5)
  __builtin_amdgcn_global_load_lds((gas_void*)g, (las_void*)l, 16, 0, 0);
}

#define VMW(n) asm volatile("s_waitcnt vmcnt(" #n ")" ::: "memory")
#define SBAR() __builtin_amdgcn_s_barrier()
#define SFENCE() __builtin_amdgcn_sched_barrier(0)

__device__ __forceinline__ float blockSum256(float v) {
  __shared__ float sh[4];
  #pragma unroll
  for (int o = 32; o; o >>= 1) v += __shfl_xor(v, o, 64);
  int lane = threadIdx.x & 63, w = threadIdx.x >> 6;
  __syncthreads();
  if (lane == 0) sh[w] = v;
  __syncthreads();
  return sh[0] + sh[1] + sh[2] + sh[3];
}

// Swizzled LDS fragment read: tile rows of 64 bf16 (8 chunks of 16B),
// chunk stored at (cb ^ (row&7)). Matches the pre-swizzled global source.
__device__ __forceinline__ bf16x8 lds_frag(const unsigned short* base, int row, int cb) {
  return *(const bf16x8*)(base + row*64 + (((cb ^ (row & 7))) << 3));
}

// ---------------- K0: fp32 -> bf16 conversion ----------------
__global__ __launch_bounds__(256) void k_convert(const float* __restrict__ x,
    const float* __restrict__ w, uint2* __restrict__ x16, uint2* __restrict__ w16) {
  const int nx4 = 15*1024*CDIM/4;
  const int nw4 = 15*DDIM*CDIM/4;
  int stride = gridDim.x * blockDim.x;
  for (int i = blockIdx.x*blockDim.x + threadIdx.x; i < nx4; i += stride) {
    float4 v = ((const float4*)x)[i];
    x16[i] = make_uint2((unsigned)f2bf(v.x) | ((unsigned)f2bf(v.y) << 16),
                        (unsigned)f2bf(v.z) | ((unsigned)f2bf(v.w) << 16));
  }
  for (int i = blockIdx.x*blockDim.x + threadIdx.x; i < nw4; i += stride) {
    float4 v = ((const float4*)w)[i];
    w16[i] = make_uint2((unsigned)f2bf(v.x) | ((unsigned)f2bf(v.y) << 16),
                        (unsigned)f2bf(v.z) | ((unsigned)f2bf(v.w) << 16));
  }
}

// ---------------- K1: total_k = [src_k; tgt] @ W_add[ik]^T + b_add (bf16 out) ----------------
// Depth-2 pipeline: BM=128 BN=256 BK=64, 8 waves (2Mx4N), 3 LDS buffers (144KB),
// counted vmcnt(6) (T4), raw s_barrier, swizzled staging (T2), setprio (T5),
// XCD-aware bid mapping (T1), fused column-sum epilogue.
__global__ __launch_bounds__(512, 2) void k_gemm1(
    const unsigned short* __restrict__ x16,     // [15][1024][2048]
    const unsigned short* __restrict__ w16,     // [15][512][2048]
    const float* __restrict__ b_add,            // [15][512]
    const int* __restrict__ subj_p,
    unsigned short* __restrict__ t16,           // [14][2048][512]
    float* __restrict__ scol)                   // [14][512] (pre-zeroed)
{
  // grid 512: bid%8 == k%8 so each k's 32 blocks share one XCD L2
  int bid = blockIdx.x;
  int k, t;
  if (bid < 256) { k = bid & 7; t = bid >> 3; }
  else { int b2 = bid - 256; k = 8 + (b2 & 7); t = b2 >> 3; if (k >= 14) return; }
  int mt = t >> 1, nt = t & 1;
  const int subj = *subj_p;
  int ik = (k < subj) ? k : (k + 1);

  __shared__ unsigned short lds[3*384*64];   // buf: A[128][64] @0, B[256][64] @8192

  int tid = threadIdx.x;
  int lane = tid & 63;
  int w = tid >> 6;           // 0..7
  int wm = w >> 2, wn = w & 3;
  int rr = lane >> 3;
  int cc8 = ((lane & 7) ^ rr) << 3;   // pre-swizzled source chunk (r0 is 8-aligned)

  const unsigned short* Bb = w16 + (size_t)ik * DDIM * CDIM;

  f32x4 acc[4][4];
  #pragma unroll
  for (int a = 0; a < 4; a++)
    #pragma unroll
    for (int b = 0; b < 4; b++) acc[a][b] = f32x4{0.f,0.f,0.f,0.f};

  auto stage = [&](int tt, int bufi) {
    unsigned short* buf = lds + bufi*(384*64);
    int ks = tt*64;
    #pragma unroll
    for (int i = 0; i < 2; i++) {           // A: 16 pieces, 2 per wave
      int r0 = (w*2 + i)*8;
      int gr = mt*128 + r0 + rr;
      int xrow = ((gr < 1024) ? ik : subj)*1024 + (gr & 1023);
      async16(x16 + (size_t)xrow*CDIM + ks + cc8, buf + r0*64);
    }
    #pragma unroll
    for (int i = 0; i < 4; i++) {           // B: 32 pieces, 4 per wave
      int r0 = (w*4 + i)*8;
      int gn = nt*256 + r0 + rr;
      async16(Bb + (size_t)gn*CDIM + ks + cc8, buf + 8192 + r0*64);
    }
  };

  auto compute = [&](int bufi) {
    const unsigned short* A = lds + bufi*(384*64);
    const unsigned short* B = A + 8192;
    bf16x8 af[4][2], bfr[4][2];
    #pragma unroll
    for (int a = 0; a < 4; a++)
      #pragma unroll
      for (int ksl = 0; ksl < 2; ksl++)
        af[a][ksl] = lds_frag(A, wm*64 + a*16 + (lane & 15), ksl*4 + (lane >> 4));
    #pragma unroll
    for (int bb = 0; bb < 4; bb++)
      #pragma unroll
      for (int ksl = 0; ksl < 2; ksl++)
        bfr[bb][ksl] = lds_frag(B, wn*64 + bb*16 + (lane & 15), ksl*4 + (lane >> 4));
    __builtin_amdgcn_s_setprio(1);
    #pragma unroll
    for (int a = 0; a < 4; a++)
      #pragma unroll
      for (int bb = 0; bb < 4; bb++) {
        acc[a][bb] = __builtin_amdgcn_mfma_f32_16x16x32_bf16(af[a][0], bfr[bb][0], acc[a][bb], 0, 0, 0);
        acc[a][bb] = __builtin_amdgcn_mfma_f32_16x16x32_bf16(af[a][1], bfr[bb][1], acc[a][bb], 0, 0, 0);
      }
    __builtin_amdgcn_s_setprio(0);
  };

  stage(0, 0);
  stage(1, 1);
  VMW(6); SBAR(); SFENCE();                 // tile0 staged (12 out -> wait oldest 6)

  int cur = 0;
  for (int tt = 0; tt < 30; ++tt) {
    int nb = cur + 2; if (nb >= 3) nb -= 3;
    stage(tt + 2, nb);                      // prefetch depth 2
    compute(cur);
    VMW(6); SBAR(); SFENCE();               // tile tt+1 staged; never drain to 0
    cur = (cur == 2) ? 0 : cur + 1;
  }
  compute(cur);                             // tile 30
  VMW(0); SBAR(); SFENCE();                 // tail: tile 31 fully staged
  cur = (cur == 2) ? 0 : cur + 1;
  compute(cur);                             // tile 31

  const float* bias = b_add + ik*DDIM;
  #pragma unroll
  for (int bb = 0; bb < 4; bb++) {
    int coln = nt*256 + wn*64 + bb*16 + (lane & 15);
    float bv = bias[coln];
    float cs = 0.f;
    #pragma unroll
    for (int a = 0; a < 4; a++) {
      #pragma unroll
      for (int r = 0; r < 4; r++) {
        int rowm = mt*128 + wm*64 + a*16 + ((lane >> 4) << 2) + r;   // C layout m89/m91
        float val = acc[a][bb][r] + bv;
        t16[((size_t)k*2048 + rowm)*DDIM + coln] = f2bf(val);
        cs += val;
      }
    }
    // column partial over this wave's 64 rows: combine the 4 row-groups
    cs += __shfl_xor(cs, 16, 64);
    cs += __shfl_xor(cs, 32, 64);
    if ((lane >> 4) == 0) atomicAdd(&scol[k*DDIM + coln], cs);
  }
}

// ---------------- K2a: per-row sq / softmax max / inv-sumexp ----------------
__global__ __launch_bounds__(256) void k_rowred(const unsigned short* __restrict__ t16,
    float* __restrict__ sq, float* __restrict__ rmax, float* __restrict__ rinv)
{
  int wid = blockIdx.x*4 + (threadIdx.x >> 6);   // 0..28671 = k*2048 + r
  int lane = threadIdx.x & 63;
  uint4 v = *(const uint4*)(t16 + (size_t)wid * DDIM + lane*8);
  unsigned uu[4] = {v.x, v.y, v.z, v.w};
  float f[8];
  #pragma unroll
  for (int q = 0; q < 4; q++) {
    f[2*q]   = bf2f((unsigned short)(uu[q] & 0xffffu));
    f[2*q+1] = bf2f((unsigned short)(uu[q] >> 16));
  }
  float s2 = 0.f, mx = -3.4e38f;
  #pragma unroll
  for (int j = 0; j < 8; j++) { s2 += f[j]*f[j]; mx = fmaxf(mx, f[j]); }
  #pragma unroll
  for (int o = 32; o; o >>= 1) { s2 += __shfl_xor(s2, o, 64); mx = fmaxf(mx, __shfl_xor(mx, o, 64)); }
  float se = 0.f;
  #pragma unroll
  for (int j = 0; j < 8; j++) se += __expf(f[j] - mx);
  #pragma unroll
  for (int o = 32; o; o >>= 1) se += __shfl_xor(se, o, 64);
  if (lane == 0) { sq[wid] = s2; rmax[wid] = mx; rinv[wid] = 1.f/se; }
}

// ---------------- K2c: bandwidth -> exp2 coefficients ----------------
__global__ __launch_bounds__(256) void k_bw(const float* __restrict__ sq,
    const float* __restrict__ scol, float* __restrict__ c2)
{
  int k = blockIdx.x;
  float a = 0.f;
  for (int r = threadIdx.x; r < 2048; r += 256) a += sq[k*2048 + r];
  float b = 0.f;
  for (int d = threadIdx.x; d < 512; d += 256) { float v = scol[k*512 + d]; b += v*v; }
  float atot = blockSum256(a);
  float btot = blockSum256(b);
  if (threadIdx.x == 0) {
    // sum(d2) = 2m*sum(sq) - 2*|sum_rows|^2 ; bandwidth = sum/(m^2-m) / 2^(5//2)
    float sumd2 = 2.f*2048.f*atot - 2.f*btot;
    float bw = sumd2 / (2048.f*2048.f - 2048.f) * 0.25f;
    #pragma unroll
    for (int i = 0; i < 5; i++)
      c2[k*5 + i] = -1.4426950408889634f / (bw * (float)(1 << i));
  }
}

// ---------------- K2d: Gram + signed kernel-sum (MMD), upper-tri tiles ----------------
// 2-buffer depth-1 pipeline (65KB -> 2 blocks/CU), XCD-aware bid, exp-chain epilogue.
__global__ __launch_bounds__(256, 2) void k_mmd(
    const unsigned short* __restrict__ t16,
    const float* __restrict__ sq,
    const float* __restrict__ c2,
    float* __restrict__ g_acc)
{
  // grid 2176: bid%8 == k%8 -> per-k 2.1MB strip stays in one XCD's L2
  int bid = blockIdx.x;
  int k, pr;
  if (bid < 1088) { k = bid & 7; pr = bid >> 3; }
  else { int b2 = bid - 1088; k = 8 + (b2 & 7); pr = b2 >> 3; if (k >= 14) return; }
  int tri = pr;
  int it = 0;
  while (tri >= 16 - it) { tri -= 16 - it; it++; }
  int jt = it + tri;               // it <= jt

  const unsigned short* T = t16 + (size_t)k * 2048 * DDIM;

  __shared__ unsigned short lds[2*256*64];  // buf: A[128][64] @0, B[128][64] @8192
  __shared__ float sqs[256];

  int tid = threadIdx.x;
  int lane = tid & 63;
  int w = tid >> 6;                // 0..3
  int wm = w >> 1, wn = w & 1;
  int rr = lane >> 3;
  int cc8 = ((lane & 7) ^ rr) << 3;

  f32x4 acc[4][4];
  #pragma unroll
  for (int a = 0; a < 4; a++)
    #pragma unroll
    for (int b = 0; b < 4; b++) acc[a][b] = f32x4{0.f,0.f,0.f,0.f};

  auto stage = [&](int tt, int bufi) {
    unsigned short* buf = lds + bufi*(256*64);
    int ks = tt*64;
    #pragma unroll
    for (int i = 0; i < 4; i++) {           // A: 16 pieces, 4 per wave
      int r0 = (w*4 + i)*8;
      async16(T + (size_t)(it*128 + r0 + rr)*DDIM + ks + cc8, buf + r0*64);
    }
    #pragma unroll
    for (int i = 0; i < 4; i++) {           // B: 16 pieces, 4 per wave
      int r0 = (w*4 + i)*8;
      async16(T + (size_t)(jt*128 + r0 + rr)*DDIM + ks + cc8, buf + 8192 + r0*64);
    }
  };

  auto compute = [&](int bufi) {
    const unsigned short* A = lds + bufi*(256*64);
    const unsigned short* B = A + 8192;
    bf16x8 af[4][2], bfr[4][2];
    #pragma unroll
    for (int a = 0; a < 4; a++)
      #pragma unroll
      for (int ksl = 0; ksl < 2; ksl++)
        af[a][ksl] = lds_frag(A, wm*64 + a*16 + (lane & 15), ksl*4 + (lane >> 4));
    #pragma unroll
    for (int bb = 0; bb < 4; bb++)
      #pragma unroll
      for (int ksl = 0; ksl < 2; ksl++)
        bfr[bb][ksl] = lds_frag(B, wn*64 + bb*16 + (lane & 15), ksl*4 + (lane >> 4));
    __builtin_amdgcn_s_setprio(1);
    #pragma unroll
    for (int a = 0; a < 4; a++)
      #pragma unroll
      for (int bb = 0; bb < 4; bb++) {
        acc[a][bb] = __builtin_amdgcn_mfma_f32_16x16x32_bf16(af[a][0], bfr[bb][0], acc[a][bb], 0, 0, 0);
        acc[a][bb] = __builtin_amdgcn_mfma_f32_16x16x32_bf16(af[a][1], bfr[bb][1], acc[a][bb], 0, 0, 0);
      }
    __builtin_amdgcn_s_setprio(0);
  };

  stage(0, 0);
  VMW(0); SBAR(); SFENCE();

  int cur = 0;
  for (int tt = 0; tt < 7; ++tt) {
    stage(tt + 1, cur ^ 1);                 // depth-1 prefetch, overlaps compute
    compute(cur);
    VMW(0); SBAR(); SFENCE();
    cur ^= 1;
  }
  compute(cur);                             // tile 7

  if (tid < 128) sqs[tid] = sq[k*2048 + it*128 + tid];
  else           sqs[tid] = sq[k*2048 + jt*128 + (tid - 128)];
  __syncthreads();

  // kernels: sum_i exp2(c_i*d2), c_i = c4*2^(4-i) -> z^16+z^8+z^4+z^2+z, z=exp2(c4*d2)
  float c4 = c2[k*5 + 4];
  float part = 0.f;
  #pragma unroll
  for (int a = 0; a < 4; a++) {
    #pragma unroll
    for (int bb = 0; bb < 4; bb++) {
      int rj = wn*64 + bb*16 + (lane & 15);
      float sj = sqs[128 + rj];
      #pragma unroll
      for (int r = 0; r < 4; r++) {
        int ri = wm*64 + a*16 + ((lane >> 4) << 2) + r;
        float d2 = sqs[ri] + sj - 2.f*acc[a][bb][r];
        float z = exp2f(c4*d2);
        float z2 = z*z, z4 = z2*z2, z8 = z4*z4;
        part += z + z2 + z4 + z8 + z8*z8;
      }
    }
  }
  float tot = blockSum256(part);
  if (tid == 0) {
    float sgn = ((it < 8) == (jt < 8)) ? 1.f : -1.f;   // XX/YY: + ; XY/YX: -
    float wgt = (it == jt) ? 1.f : 2.f;                 // symmetry
    atomicAdd(&g_acc[k], sgn * wgt * tot);
  }
}

// ---------------- K3: heads = disc + logits(+cls KL, +pred accum) fused ----------------
__global__ __launch_bounds__(256) void k_heads(const unsigned short* __restrict__ t16,
    const float* __restrict__ rmax, const float* __restrict__ rinv,
    const float* __restrict__ W_cls, const float* __restrict__ b_cls,
    const float* __restrict__ y, const int* __restrict__ subj_p,
    float* __restrict__ g_acc, float* __restrict__ pacc)
{
  if (blockIdx.x < 2048) {
    int b = blockIdx.x;              // 1024 rows x 2 half-rows
    int row = b >> 1;                // source rows only
    int d = ((b & 1) << 8) + threadIdx.x;
    float p[14];
    #pragma unroll
    for (int k = 0; k < 14; k++) {
      float tv = bf2f(t16[((size_t)(k*2048 + row))*DDIM + d]);
      p[k] = __expf(tv - rmax[k*2048 + row]) * rinv[k*2048 + row];
    }
    float s = 0.f;
    #pragma unroll
    for (int i2 = 0; i2 < 14; i2++)
      #pragma unroll
      for (int j2 = i2+1; j2 < 14; j2++)
        s += fabsf(p[i2] - p[j2]);
    float tot = blockSum256(s);
    if (threadIdx.x == 0) atomicAdd(&g_acc[14 + (b & 7)], tot);
  } else {
    __shared__ float shk[4];
    int bid = blockIdx.x - 2048;
    int w = threadIdx.x >> 6;
    int lane = threadIdx.x & 63;
    int wid = bid*4 + w;             // k*2048 + r (4 rows, same k, same half)
    int k = wid >> 11, r = wid & 2047;
    uint4 v = *(const uint4*)(t16 + (size_t)wid * DDIM + lane*8);
    unsigned uu[4] = {v.x, v.y, v.z, v.w};
    float f[8];
    #pragma unroll
    for (int q = 0; q < 4; q++) {
      f[2*q]   = fmaxf(bf2f((unsigned short)(uu[q] & 0xffffu)), 0.f);
      f[2*q+1] = fmaxf(bf2f((unsigned short)(uu[q] >> 16)), 0.f);
    }
    const float* Wc = W_cls + k*3*DDIM;
    int d0 = lane*8;
    float l0 = 0.f, l1 = 0.f, l2 = 0.f;
    #pragma unroll
    for (int j = 0; j < 8; j++) {
      l0 += f[j]*Wc[d0+j];
      l1 += f[j]*Wc[DDIM + d0+j];
      l2 += f[j]*Wc[2*DDIM + d0+j];
    }
    #pragma unroll
    for (int o = 32; o; o >>= 1) {
      l0 += __shfl_xor(l0, o, 64); l1 += __shfl_xor(l1, o, 64); l2 += __shfl_xor(l2, o, 64);
    }
    if (r < 1024) {                  // src rows -> cls KL
      if (lane == 0) {
        l0 += b_cls[k*3+0]; l1 += b_cls[k*3+1]; l2 += b_cls[k*3+2];
        float mx = fmaxf(l0, fmaxf(l1, l2));
        float lse = mx + __logf(__expf(l0-mx) + __expf(l1-mx) + __expf(l2-mx));
        int subj = *subj_p;
        int ik = (k < subj) ? k : k+1;
        const float* yr = y + ((size_t)(ik*1024 + r))*3;
        float tl = (yr[0] > 0.5f) ? l0 : ((yr[1] > 0.5f) ? l1 : l2);
        shk[w] = lse - tl;
      }
      __syncthreads();
      if (threadIdx.x == 0)
        atomicAdd(&g_acc[22 + k], shk[0] + shk[1] + shk[2] + shk[3]);
    } else {                         // tgt rows -> pred prob accumulation
      if (lane == 0) {
        l0 += b_cls[k*3+0]; l1 += b_cls[k*3+1]; l2 += b_cls[k*3+2];
        float mx = fmaxf(l0, fmaxf(l1, l2));
        float e0 = __expf(l0-mx), e1 = __expf(l1-mx), e2 = __expf(l2-mx);
        float inv = 1.f/(e0+e1+e2);
        int j = r - 1024;
        atomicAdd(&pacc[j*3 + 0], e0*inv);
        atomicAdd(&pacc[j*3 + 1], e1*inv);
        atomicAdd(&pacc[j*3 + 2], e2*inv);
      }
    }
  }
}

// ---------------- K6: pred (argmax of summed softmax over k) ----------------
__global__ __launch_bounds__(256) void k_pred(const float* __restrict__ pacc,
    const float* __restrict__ y, const int* __restrict__ subj_p, float* __restrict__ g_acc)
{
  int j = blockIdx.x*256 + threadIdx.x;   // 0..1023
  int subj = *subj_p;
  float p0 = pacc[j*3+0], p1 = pacc[j*3+1], p2 = pacc[j*3+2];
  int pa = 0; float pm = p0;
  if (p1 > pm) { pa = 1; pm = p1; }
  if (p2 > pm) { pa = 2; }
  const float* yt = y + ((size_t)(subj*1024 + j))*3;
  int ya = 0; float ym = yt[0];
  if (yt[1] > ym) { ya = 1; ym = yt[1]; }
  if (yt[2] > ym) { ya = 2; }
  float tot = blockSum256((pa == ya) ? 1.f : 0.f);
  if (threadIdx.x == 0) atomicAdd(&g_acc[36], tot);
}

// ---------------- K7: finalize ----------------
__global__ void k_fin(const float* __restrict__ g_acc, float* __restrict__ out)
{
  if (threadIdx.x == 0 && blockIdx.x == 0) {
    float s = 0.f;
    for (int k = 0; k < 14; k++) s += g_acc[k];
    float disc = 0.f;
    for (int i = 14; i < 22; i++) disc += g_acc[i];
    float cls = 0.f;
    for (int i = 22; i < 36; i++) cls += g_acc[i];
    out[0] = 0.1f * s / (14.f * 1024.f * 1024.f);
    out[1] = 0.4f * disc * (2.f / (14.f*13.f)) / (1024.f*512.f);
    out[2] = cls / (14.f*1024.f);
    out[3] = g_acc[36];
    out[4] = 1024.f;
  }
}

// ---------------- launch ----------------
extern "C" void kernel_launch(void* const* d_in, const int* in_sizes, int n_in,
                              void* d_out, int out_size, void* d_ws, size_t ws_size,
                              hipStream_t stream)
{
  (void)in_sizes; (void)n_in; (void)out_size; (void)ws_size;
  const float* x     = (const float*)d_in[0];
  const float* y     = (const float*)d_in[1];
  const float* W_add = (const float*)d_in[3];
  const float* b_add = (const float*)d_in[4];
  const float* W_cls = (const float*)d_in[5];
  const float* b_cls = (const float*)d_in[6];
  const int*   subj  = (const int*)d_in[7];

  char* ws = (char*)d_ws;
  size_t o = 0;
  auto take = [&](size_t b) { char* p = ws + o; o += (b + 255) & ~(size_t)255; return p; };
  unsigned short* X16 = (unsigned short*)take((size_t)15*1024*2048*2);   // 63 MB
  unsigned short* W16 = (unsigned short*)take((size_t)15*512*2048*2);    // 31.5 MB
  unsigned short* T16 = (unsigned short*)take((size_t)14*2048*512*2);    // 29.4 MB
  float* SQ   = (float*)take((size_t)14*2048*4);
  float* RMAX = (float*)take((size_t)14*2048*4);
  float* RINV = (float*)take((size_t)14*2048*4);
  float* C2   = (float*)take(512);
  // zero-init region (single memset): SCOL | PACC | ACC
  float* SCOL = (float*)take((size_t)14*512*4);     // 28672 B
  float* PACC = (float*)take((size_t)1024*3*4);     // 12288 B
  float* ACC  = (float*)take(256);                  // [0..13] mmd, [14..21] disc, [22..35] cls, [36] pred

  hipMemsetAsync(SCOL, 0, 14*512*4 + 1024*3*4 + 256, stream);

  k_convert<<<2048, 256, 0, stream>>>(x, W_add, (uint2*)X16, (uint2*)W16);
  k_gemm1 <<<512, 512, 0, stream>>>(X16, W16, b_add, subj, T16, SCOL);
  k_rowred<<<14*2048/4, 256, 0, stream>>>(T16, SQ, RMAX, RINV);
  k_bw    <<<14, 256, 0, stream>>>(SQ, SCOL, C2);
  k_mmd   <<<2176, 256, 0, stream>>>(T16, SQ, C2, ACC);
  k_heads <<<2048 + 14*2048/4, 256, 0, stream>>>(T16, RMAX, RINV, W_cls, b_cls, y, subj, ACC, PACC);
  k_pred  <<<4, 256, 0, stream>>>(PACC, y, subj, ACC);
  k_fin   <<<1, 64, 0, stream>>>(ACC, (float*)d_out);
}

// Round 12
// 448.941 us; speedup vs baseline: 1.1749x; 1.0065x over previous
//
#include <hip/hip_runtime.h>
#include <hip/hip_bf16.h>
#include <stdint.h>

// ---------------- types & helpers ----------------
typedef __attribute__((ext_vector_type(8))) __bf16 bf16x8;
typedef __attribute__((ext_vector_type(4))) float f32x4;

#define CDIM 2048
#define DDIM 512

__device__ __forceinline__ unsigned f2bf(float f) {
  union { float f; unsigned u; } a; a.f = f;
  unsigned r = a.u + 0x7FFFu + ((a.u >> 16) & 1u);   // RNE to bf16
  return r >> 16;
}
__device__ __forceinline__ float bf2f(unsigned short h) {
  union { unsigned u; float f; } a; a.u = ((unsigned)h) << 16;
  return a.f;
}

typedef const __attribute__((address_space(1))) void gas_void;
typedef __attribute__((address_space(3))) void las_void;
__device__ __forceinline__ void async16(const void* g, void* l) {
  // wave-uniform LDS base; HW adds lane*16 (guide §5)
  __builtin_amdgcn_global_load_lds((gas_void*)g, (las_void*)l, 16, 0, 0);
}

#define VMW(n) asm volatile("s_waitcnt vmcnt(" #n ")" ::: "memory")
#define SBAR() __builtin_amdgcn_s_barrier()
#define SFENCE() __builtin_amdgcn_sched_barrier(0)

__device__ __forceinline__ float blockSum256(float v) {
  __shared__ float sh[4];
  #pragma unroll
  for (int o = 32; o; o >>= 1) v += __shfl_xor(v, o, 64);
  int lane = threadIdx.x & 63, w = threadIdx.x >> 6;
  __syncthreads();
  if (lane == 0) sh[w] = v;
  __syncthreads();
  return sh[0] + sh[1] + sh[2] + sh[3];
}

// Swizzled LDS fragment read: tile rows of 64 bf16 (8 chunks of 16B),
// chunk stored at (cb ^ (row&7)). Matches the pre-swizzled global source.
__device__ __forceinline__ bf16x8 lds_frag(const unsigned short* base, int row, int cb) {
  return *(const bf16x8*)(base + row*64 + (((cb ^ (row & 7))) << 3));
}

// ---------------- K0: fp32 -> bf16 conversion (8 floats/thread, 16B stores) ----------------
__global__ __launch_bounds__(256) void k_convert(const float* __restrict__ x,
    const float* __restrict__ w, uint4* __restrict__ x16, uint4* __restrict__ w16) {
  const int nx8 = 15*1024*CDIM/8;    // 3,932,160 uint4 outputs
  const int nw8 = 15*DDIM*CDIM/8;    // 1,966,080
  int stride = gridDim.x * blockDim.x;
  int t0 = blockIdx.x*blockDim.x + threadIdx.x;
  const float4* xv = (const float4*)x;
  const float4* wv = (const float4*)w;
  for (int i = t0; i < nx8; i += stride) {
    float4 a = xv[2*i], b = xv[2*i+1];
    uint4 o;
    o.x = f2bf(a.x) | (f2bf(a.y) << 16);
    o.y = f2bf(a.z) | (f2bf(a.w) << 16);
    o.z = f2bf(b.x) | (f2bf(b.y) << 16);
    o.w = f2bf(b.z) | (f2bf(b.w) << 16);
    x16[i] = o;
  }
  for (int i = t0; i < nw8; i += stride) {
    float4 a = wv[2*i], b = wv[2*i+1];
    uint4 o;
    o.x = f2bf(a.x) | (f2bf(a.y) << 16);
    o.y = f2bf(a.z) | (f2bf(a.w) << 16);
    o.z = f2bf(b.x) | (f2bf(b.y) << 16);
    o.w = f2bf(b.z) | (f2bf(b.w) << 16);
    w16[i] = o;
  }
}

// ---------------- K1: total_k = [src_k; tgt] @ W_add[ik]^T + b_add (bf16 out) ----------------
// Depth-2 pipeline: BM=128 BN=256 BK=64, 8 waves (2Mx4N), 3 LDS buffers (144KB),
// counted vmcnt(6) (T4), raw s_barrier, swizzled staging (T2), setprio (T5),
// XCD-aware bid mapping (T1). Epilogue fuses: column-sums (for MMD bandwidth),
// per-row sum(v^2) and sum(exp(v)) (replaces k_rowred; no-max softmax is safe:
// |v| <= ~6 here so exp() and sums are well within fp32 range).
__global__ __launch_bounds__(512, 2) void k_gemm1(
    const unsigned short* __restrict__ x16,     // [15][1024][2048]
    const unsigned short* __restrict__ w16,     // [15][512][2048]
    const float* __restrict__ b_add,            // [15][512]
    const int* __restrict__ subj_p,
    unsigned short* __restrict__ t16,           // [14][2048][512]
    float* __restrict__ scol,                   // [14][512]  (pre-zeroed)
    float* __restrict__ rowsq,                  // [14][2048] (pre-zeroed)
    float* __restrict__ rowex)                  // [14][2048] (pre-zeroed)
{
  // grid 512: bid%8 == k%8 so each k's 32 blocks share one XCD L2
  int bid = blockIdx.x;
  int k, t;
  if (bid < 256) { k = bid & 7; t = bid >> 3; }
  else { int b2 = bid - 256; k = 8 + (b2 & 7); t = b2 >> 3; if (k >= 14) return; }
  int mt = t >> 1, nt = t & 1;
  const int subj = *subj_p;
  int ik = (k < subj) ? k : (k + 1);

  __shared__ unsigned short lds[3*384*64];   // buf: A[128][64] @0, B[256][64] @8192

  int tid = threadIdx.x;
  int lane = tid & 63;
  int w = tid >> 6;           // 0..7
  int wm = w >> 2, wn = w & 3;
  int rr = lane >> 3;
  int cc8 = ((lane & 7) ^ rr) << 3;   // pre-swizzled source chunk (r0 is 8-aligned)

  const unsigned short* Bb = w16 + (size_t)ik * DDIM * CDIM;

  f32x4 acc[4][4];
  #pragma unroll
  for (int a = 0; a < 4; a++)
    #pragma unroll
    for (int b = 0; b < 4; b++) acc[a][b] = f32x4{0.f,0.f,0.f,0.f};

  auto stage = [&](int tt, int bufi) {
    unsigned short* buf = lds + bufi*(384*64);
    int ks = tt*64;
    #pragma unroll
    for (int i = 0; i < 2; i++) {           // A: 16 pieces, 2 per wave
      int r0 = (w*2 + i)*8;
      int gr = mt*128 + r0 + rr;
      int xrow = ((gr < 1024) ? ik : subj)*1024 + (gr & 1023);
      async16(x16 + (size_t)xrow*CDIM + ks + cc8, buf + r0*64);
    }
    #pragma unroll
    for (int i = 0; i < 4; i++) {           // B: 32 pieces, 4 per wave
      int r0 = (w*4 + i)*8;
      int gn = nt*256 + r0 + rr;
      async16(Bb + (size_t)gn*CDIM + ks + cc8, buf + 8192 + r0*64);
    }
  };

  auto compute = [&](int bufi) {
    const unsigned short* A = lds + bufi*(384*64);
    const unsigned short* B = A + 8192;
    bf16x8 af[4][2], bfr[4][2];
    #pragma unroll
    for (int a = 0; a < 4; a++)
      #pragma unroll
      for (int ksl = 0; ksl < 2; ksl++)
        af[a][ksl] = lds_frag(A, wm*64 + a*16 + (lane & 15), ksl*4 + (lane >> 4));
    #pragma unroll
    for (int bb = 0; bb < 4; bb++)
      #pragma unroll
      for (int ksl = 0; ksl < 2; ksl++)
        bfr[bb][ksl] = lds_frag(B, wn*64 + bb*16 + (lane & 15), ksl*4 + (lane >> 4));
    __builtin_amdgcn_s_setprio(1);
    #pragma unroll
    for (int a = 0; a < 4; a++)
      #pragma unroll
      for (int bb = 0; bb < 4; bb++) {
        acc[a][bb] = __builtin_amdgcn_mfma_f32_16x16x32_bf16(af[a][0], bfr[bb][0], acc[a][bb], 0, 0, 0);
        acc[a][bb] = __builtin_amdgcn_mfma_f32_16x16x32_bf16(af[a][1], bfr[bb][1], acc[a][bb], 0, 0, 0);
      }
    __builtin_amdgcn_s_setprio(0);
  };

  stage(0, 0);
  stage(1, 1);
  VMW(6); SBAR(); SFENCE();                 // tile0 staged (12 out -> wait oldest 6)

  int cur = 0;
  for (int tt = 0; tt < 30; ++tt) {
    int nb = cur + 2; if (nb >= 3) nb -= 3;
    stage(tt + 2, nb);                      // prefetch depth 2
    compute(cur);
    VMW(6); SBAR(); SFENCE();               // tile tt+1 staged; never drain to 0
    cur = (cur == 2) ? 0 : cur + 1;
  }
  compute(cur);                             // tile 30
  VMW(0); SBAR(); SFENCE();                 // tail: tile 31 fully staged
  cur = (cur == 2) ? 0 : cur + 1;
  compute(cur);                             // tile 31

  const float* bias = b_add + ik*DDIM;
  int coln[4]; float bv[4];
  #pragma unroll
  for (int bb = 0; bb < 4; bb++) {
    coln[bb] = nt*256 + wn*64 + bb*16 + (lane & 15);
    bv[bb] = bias[coln[bb]];
  }
  float cs[4] = {0.f, 0.f, 0.f, 0.f};
  #pragma unroll
  for (int a = 0; a < 4; a++) {
    #pragma unroll
    for (int r = 0; r < 4; r++) {
      int rowm = mt*128 + wm*64 + a*16 + ((lane >> 4) << 2) + r;   // C layout m89/m91
      float sqp = 0.f, exq = 0.f;
      #pragma unroll
      for (int bb = 0; bb < 4; bb++) {
        float val = acc[a][bb][r] + bv[bb];
        t16[((size_t)k*2048 + rowm)*DDIM + coln[bb]] = (unsigned short)f2bf(val);
        sqp += val*val;
        exq += __expf(val);
        cs[bb] += val;
      }
      // reduce over the 16 lanes of this row-group (cols): lanes lane&15
      #pragma unroll
      for (int o2 = 1; o2 <= 8; o2 <<= 1) {
        sqp += __shfl_xor(sqp, o2, 64);
        exq += __shfl_xor(exq, o2, 64);
      }
      if ((lane & 15) == 0) {     // lanes 0,16,32,48: distinct rows
        atomicAdd(&rowsq[k*2048 + rowm], sqp);
        atomicAdd(&rowex[k*2048 + rowm], exq);
      }
    }
  }
  #pragma unroll
  for (int bb = 0; bb < 4; bb++) {
    float c = cs[bb];
    c += __shfl_xor(c, 16, 64);
    c += __shfl_xor(c, 32, 64);
    if ((lane >> 4) == 0) atomicAdd(&scol[k*DDIM + coln[bb]], c);
  }
}

// ---------------- K2c: bandwidth -> exp2 coefficients ----------------
__global__ __launch_bounds__(256) void k_bw(const float* __restrict__ sq,
    const float* __restrict__ scol, float* __restrict__ c2)
{
  int k = blockIdx.x;
  float a = 0.f;
  for (int r = threadIdx.x; r < 2048; r += 256) a += sq[k*2048 + r];
  float b = 0.f;
  for (int d = threadIdx.x; d < 512; d += 256) { float v = scol[k*512 + d]; b += v*v; }
  float atot = blockSum256(a);
  float btot = blockSum256(b);
  if (threadIdx.x == 0) {
    // sum(d2) = 2m*sum(sq) - 2*|sum_rows|^2 ; bandwidth = sum/(m^2-m) / 2^(5//2)
    float sumd2 = 2.f*2048.f*atot - 2.f*btot;
    float bw = sumd2 / (2048.f*2048.f - 2048.f) * 0.25f;
    #pragma unroll
    for (int i = 0; i < 5; i++)
      c2[k*5 + i] = -1.4426950408889634f / (bw * (float)(1 << i));
  }
}

// ---------------- K2d: Gram + signed kernel-sum (MMD), upper-tri tiles ----------------
// 2-buffer depth-1 pipeline (65KB -> 2 blocks/CU), XCD-aware bid, exp-chain epilogue.
__global__ __launch_bounds__(256, 2) void k_mmd(
    const unsigned short* __restrict__ t16,
    const float* __restrict__ sq,
    const float* __restrict__ c2,
    float* __restrict__ g_acc)
{
  // grid 2176: bid%8 == k%8 -> per-k 2.1MB strip stays in one XCD's L2
  int bid = blockIdx.x;
  int k, pr;
  if (bid < 1088) { k = bid & 7; pr = bid >> 3; }
  else { int b2 = bid - 1088; k = 8 + (b2 & 7); pr = b2 >> 3; if (k >= 14) return; }
  int tri = pr;
  int it = 0;
  while (tri >= 16 - it) { tri -= 16 - it; it++; }
  int jt = it + tri;               // it <= jt

  const unsigned short* T = t16 + (size_t)k * 2048 * DDIM;

  __shared__ unsigned short lds[2*256*64];  // buf: A[128][64] @0, B[128][64] @8192
  __shared__ float sqs[256];

  int tid = threadIdx.x;
  int lane = tid & 63;
  int w = tid >> 6;                // 0..3
  int wm = w >> 1, wn = w & 1;
  int rr = lane >> 3;
  int cc8 = ((lane & 7) ^ rr) << 3;

  f32x4 acc[4][4];
  #pragma unroll
  for (int a = 0; a < 4; a++)
    #pragma unroll
    for (int b = 0; b < 4; b++) acc[a][b] = f32x4{0.f,0.f,0.f,0.f};

  auto stage = [&](int tt, int bufi) {
    unsigned short* buf = lds + bufi*(256*64);
    int ks = tt*64;
    #pragma unroll
    for (int i = 0; i < 4; i++) {           // A: 16 pieces, 4 per wave
      int r0 = (w*4 + i)*8;
      async16(T + (size_t)(it*128 + r0 + rr)*DDIM + ks + cc8, buf + r0*64);
    }
    #pragma unroll
    for (int i = 0; i < 4; i++) {           // B: 16 pieces, 4 per wave
      int r0 = (w*4 + i)*8;
      async16(T + (size_t)(jt*128 + r0 + rr)*DDIM + ks + cc8, buf + 8192 + r0*64);
    }
  };

  auto compute = [&](int bufi) {
    const unsigned short* A = lds + bufi*(256*64);
    const unsigned short* B = A + 8192;
    bf16x8 af[4][2], bfr[4][2];
    #pragma unroll
    for (int a = 0; a < 4; a++)
      #pragma unroll
      for (int ksl = 0; ksl < 2; ksl++)
        af[a][ksl] = lds_frag(A, wm*64 + a*16 + (lane & 15), ksl*4 + (lane >> 4));
    #pragma unroll
    for (int bb = 0; bb < 4; bb++)
      #pragma unroll
      for (int ksl = 0; ksl < 2; ksl++)
        bfr[bb][ksl] = lds_frag(B, wn*64 + bb*16 + (lane & 15), ksl*4 + (lane >> 4));
    __builtin_amdgcn_s_setprio(1);
    #pragma unroll
    for (int a = 0; a < 4; a++)
      #pragma unroll
      for (int bb = 0; bb < 4; bb++) {
        acc[a][bb] = __builtin_amdgcn_mfma_f32_16x16x32_bf16(af[a][0], bfr[bb][0], acc[a][bb], 0, 0, 0);
        acc[a][bb] = __builtin_amdgcn_mfma_f32_16x16x32_bf16(af[a][1], bfr[bb][1], acc[a][bb], 0, 0, 0);
      }
    __builtin_amdgcn_s_setprio(0);
  };

  stage(0, 0);
  VMW(0); SBAR(); SFENCE();

  int cur = 0;
  for (int tt = 0; tt < 7; ++tt) {
    stage(tt + 1, cur ^ 1);                 // depth-1 prefetch, overlaps compute
    compute(cur);
    VMW(0); SBAR(); SFENCE();
    cur ^= 1;
  }
  compute(cur);                             // tile 7

  if (tid < 128) sqs[tid] = sq[k*2048 + it*128 + tid];
  else           sqs[tid] = sq[k*2048 + jt*128 + (tid - 128)];
  __syncthreads();

  // kernels: sum_i exp2(c_i*d2), c_i = c4*2^(4-i) -> z^16+z^8+z^4+z^2+z, z=exp2(c4*d2)
  float c4 = c2[k*5 + 4];
  float part = 0.f;
  #pragma unroll
  for (int a = 0; a < 4; a++) {
    #pragma unroll
    for (int bb = 0; bb < 4; bb++) {
      int rj = wn*64 + bb*16 + (lane & 15);
      float sj = sqs[128 + rj];
      #pragma unroll
      for (int r = 0; r < 4; r++) {
        int ri = wm*64 + a*16 + ((lane >> 4) << 2) + r;
        float d2 = sqs[ri] + sj - 2.f*acc[a][bb][r];
        float z = exp2f(c4*d2);
        float z2 = z*z, z4 = z2*z2, z8 = z4*z4;
        part += z + z2 + z4 + z8 + z8*z8;
      }
    }
  }
  float tot = blockSum256(part);
  if (tid == 0) {
    float sgn = ((it < 8) == (jt < 8)) ? 1.f : -1.f;   // XX/YY: + ; XY/YX: -
    float wgt = (it == jt) ? 1.f : 2.f;                 // symmetry
    atomicAdd(&g_acc[k], sgn * wgt * tot);
  }
}

// ---------------- K3: heads = disc + logits(+cls KL, +pred accum) fused ----------------
__global__ __launch_bounds__(256) void k_heads(const unsigned short* __restrict__ t16,
    const float* __restrict__ rowex,
    const float* __restrict__ W_cls, const float* __restrict__ b_cls,
    const float* __restrict__ y, const int* __restrict__ subj_p,
    float* __restrict__ g_acc, float* __restrict__ pacc)
{
  if (blockIdx.x < 2048) {
    int b = blockIdx.x;              // 1024 rows x 2 half-rows
    int row = b >> 1;                // source rows only
    int d = ((b & 1) << 8) + threadIdx.x;
    float p[14];
    #pragma unroll
    for (int k = 0; k < 14; k++) {
      float tv = bf2f(t16[((size_t)(k*2048 + row))*DDIM + d]);
      p[k] = __expf(tv) / rowex[k*2048 + row];   // no-max softmax (|v|<=~6)
    }
    float s = 0.f;
    #pragma unroll
    for (int i2 = 0; i2 < 14; i2++)
      #pragma unroll
      for (int j2 = i2+1; j2 < 14; j2++)
        s += fabsf(p[i2] - p[j2]);
    float tot = blockSum256(s);
    if (threadIdx.x == 0) atomicAdd(&g_acc[14 + (b & 7)], tot);
  } else {
    __shared__ float shk[4];
    int bid = blockIdx.x - 2048;
    int w = threadIdx.x >> 6;
    int lane = threadIdx.x & 63;
    int wid = bid*4 + w;             // k*2048 + r (4 rows, same k, same half)
    int k = wid >> 11, r = wid & 2047;
    uint4 v = *(const uint4*)(t16 + (size_t)wid * DDIM + lane*8);
    unsigned uu[4] = {v.x, v.y, v.z, v.w};
    float f[8];
    #pragma unroll
    for (int q = 0; q < 4; q++) {
      f[2*q]   = fmaxf(bf2f((unsigned short)(uu[q] & 0xffffu)), 0.f);
      f[2*q+1] = fmaxf(bf2f((unsigned short)(uu[q] >> 16)), 0.f);
    }
    const float* Wc = W_cls + k*3*DDIM;
    int d0 = lane*8;
    float l0 = 0.f, l1 = 0.f, l2 = 0.f;
    #pragma unroll
    for (int j = 0; j < 8; j++) {
      l0 += f[j]*Wc[d0+j];
      l1 += f[j]*Wc[DDIM + d0+j];
      l2 += f[j]*Wc[2*DDIM + d0+j];
    }
    #pragma unroll
    for (int o = 32; o; o >>= 1) {
      l0 += __shfl_xor(l0, o, 64); l1 += __shfl_xor(l1, o, 64); l2 += __shfl_xor(l2, o, 64);
    }
    if (r < 1024) {                  // src rows -> cls KL
      if (lane == 0) {
        l0 += b_cls[k*3+0]; l1 += b_cls[k*3+1]; l2 += b_cls[k*3+2];
        float mx = fmaxf(l0, fmaxf(l1, l2));
        float lse = mx + __logf(__expf(l0-mx) + __expf(l1-mx) + __expf(l2-mx));
        int subj = *subj_p;
        int ik = (k < subj) ? k : k+1;
        const float* yr = y + ((size_t)(ik*1024 + r))*3;
        float tl = (yr[0] > 0.5f) ? l0 : ((yr[1] > 0.5f) ? l1 : l2);
        shk[w] = lse - tl;
      }
      __syncthreads();
      if (threadIdx.x == 0)
        atomicAdd(&g_acc[22 + k], shk[0] + shk[1] + shk[2] + shk[3]);
    } else {                         // tgt rows -> pred prob accumulation
      if (lane == 0) {
        l0 += b_cls[k*3+0]; l1 += b_cls[k*3+1]; l2 += b_cls[k*3+2];
        float mx = fmaxf(l0, fmaxf(l1, l2));
        float e0 = __expf(l0-mx), e1 = __expf(l1-mx), e2 = __expf(l2-mx);
        float inv = 1.f/(e0+e1+e2);
        int j = r - 1024;
        atomicAdd(&pacc[j*3 + 0], e0*inv);
        atomicAdd(&pacc[j*3 + 1], e1*inv);
        atomicAdd(&pacc[j*3 + 2], e2*inv);
      }
    }
  }
}

// ---------------- K6: pred (argmax of summed softmax over k) ----------------
__global__ __launch_bounds__(256) void k_pred(const float* __restrict__ pacc,
    const float* __restrict__ y, const int* __restrict__ subj_p, float* __restrict__ g_acc)
{
  int j = blockIdx.x*256 + threadIdx.x;   // 0..1023
  int subj = *subj_p;
  float p0 = pacc[j*3+0], p1 = pacc[j*3+1], p2 = pacc[j*3+2];
  int pa = 0; float pm = p0;
  if (p1 > pm) { pa = 1; pm = p1; }
  if (p2 > pm) { pa = 2; }
  const float* yt = y + ((size_t)(subj*1024 + j))*3;
  int ya = 0; float ym = yt[0];
  if (yt[1] > ym) { ya = 1; ym = yt[1]; }
  if (yt[2] > ym) { ya = 2; }
  float tot = blockSum256((pa == ya) ? 1.f : 0.f);
  if (threadIdx.x == 0) atomicAdd(&g_acc[36], tot);
}

// ---------------- K7: finalize ----------------
__global__ void k_fin(const float* __restrict__ g_acc, float* __restrict__ out)
{
  if (threadIdx.x == 0 && blockIdx.x == 0) {
    float s = 0.f;
    for (int k = 0; k < 14; k++) s += g_acc[k];
    float disc = 0.f;
    for (int i = 14; i < 22; i++) disc += g_acc[i];
    float cls = 0.f;
    for (int i = 22; i < 36; i++) cls += g_acc[i];
    out[0] = 0.1f * s / (14.f * 1024.f * 1024.f);
    out[1] = 0.4f * disc * (2.f / (14.f*13.f)) / (1024.f*512.f);
    out[2] = cls / (14.f*1024.f);
    out[3] = g_acc[36];
    out[4] = 1024.f;
  }
}

// ---------------- launch ----------------
extern "C" void kernel_launch(void* const* d_in, const int* in_sizes, int n_in,
                              void* d_out, int out_size, void* d_ws, size_t ws_size,
                              hipStream_t stream)
{
  (void)in_sizes; (void)n_in; (void)out_size; (void)ws_size;
  const float* x     = (const float*)d_in[0];
  const float* y     = (const float*)d_in[1];
  const float* W_add = (const float*)d_in[3];
  const float* b_add = (const float*)d_in[4];
  const float* W_cls = (const float*)d_in[5];
  const float* b_cls = (const float*)d_in[6];
  const int*   subj  = (const int*)d_in[7];

  char* ws = (char*)d_ws;
  size_t o = 0;
  auto take = [&](size_t b) { char* p = ws + o; o += (b + 255) & ~(size_t)255; return p; };
  unsigned short* X16 = (unsigned short*)take((size_t)15*1024*2048*2);   // 63 MB
  unsigned short* W16 = (unsigned short*)take((size_t)15*512*2048*2);    // 31.5 MB
  unsigned short* T16 = (unsigned short*)take((size_t)14*2048*512*2);    // 29.4 MB
  float* C2   = (float*)take(512);
  // zero-init region (single memset): SQ | SE | SCOL | PACC | ACC
  float* SQ   = (float*)take((size_t)14*2048*4);    // 114688 B
  float* SE   = (float*)take((size_t)14*2048*4);    // 114688 B
  float* SCOL = (float*)take((size_t)14*512*4);     // 28672 B
  float* PACC = (float*)take((size_t)1024*3*4);     // 12288 B
  float* ACC  = (float*)take(256);                  // [0..13] mmd, [14..21] disc, [22..35] cls, [36] pred

  hipMemsetAsync(SQ, 0, (char*)ACC - (char*)SQ + 256, stream);

  k_convert<<<2048, 256, 0, stream>>>(x, W_add, (uint4*)X16, (uint4*)W16);
  k_gemm1 <<<512, 512, 0, stream>>>(X16, W16, b_add, subj, T16, SCOL, SQ, SE);
  k_bw    <<<14, 256, 0, stream>>>(SQ, SCOL, C2);
  k_mmd   <<<2176, 256, 0, stream>>>(T16, SQ, C2, ACC);
  k_heads <<<2048 + 14*2048/4, 256, 0, stream>>>(T16, SE, W_cls, b_cls, y, subj, ACC, PACC);
  k_pred  <<<4, 256, 0, stream>>>(PACC, y, subj, ACC);
  k_fin   <<<1, 64, 0, stream>>>(ACC, (float*)d_out);
}